// Round 5
// baseline (9112.391 us; speedup 1.0000x reference)
//
#include <hip/hip_runtime.h>
#include <stdint.h>

// Problem constants (from reference)
#define B_N 2048
#define T_N 100
#define H_N 256
#define L_N 128
#define NV_N 5
#define COLS (H_N + 2 * 128)   // 512 columns of all_hidden_states

#define KXH 261                // NV + H rows of Wz/Wr/Wh
#define KPAD 264               // padded K (rows 261..263 are zero-h)
#define KCS 384                // H + L rows of Wcs
#define RB 8                   // batch rows per block
#define NKQ 4                  // k-split groups (wave-pair per group)
#define KQ_LEN 66              // 264 / 4
#define CH 11                  // chunk size: 6 chunks of 11 per k-slice
#define NCH 6

// Output element offsets, concatenated in return order:
// new_h [B,H], all_hidden_states [B,T,512], seg_rep [B,H]
static constexpr long long OUT_ALLH = (long long)B_N * H_N;                     // 524288
static constexpr long long OUT_SEG  = OUT_ALLH + (long long)B_N * T_N * COLS;   // 105381888

// dynamic LDS: Pz[4][8][256], Pr[4][8][256], xhT[264][8], xgT[264][8]
static constexpr int SMEM_FLOATS = 2 * NKQ * RB * H_N + 2 * KPAD * RB;          // 20608
static constexpr int SMEM_BYTES  = SMEM_FLOATS * 4;                             // 82432

__device__ __forceinline__ float bits2f(uint32_t u) {
    union { uint32_t u; float f; } v; v.u = u; return v.f;
}
__device__ __forceinline__ uint16_t f2bf(float f) {
    union { float f; uint32_t u; } v; v.f = f;
    uint32_t r = (v.u + 0x7FFFu + ((v.u >> 16) & 1u)) >> 16;   // round-nearest-even
    return (uint16_t)r;
}

// ---------------------------------------------------------------------------
// Runtime dtype detection (unchanged, verified): majority vote on the
// fp32-exponent field of 64 words of W_cs.
// ---------------------------------------------------------------------------
__device__ __forceinline__ int detect_f32(const uint32_t* __restrict__ w) {
    int cnt = 0;
    #pragma unroll 8
    for (int i = 0; i < 64; ++i) {
        uint32_t e = (w[i] >> 23) & 0xFFu;
        cnt += (e >= 97u && e <= 130u) ? 1 : 0;
    }
    return cnt >= 32 ? 1 : 0;
}

// ---------------------------------------------------------------------------
// Dtype-abstracted element access. Index units are ELEMENTS.
// Raw2/ldraw2/cvt2: 2-element raw load (bf16: one 4B uint = 1 VGPR) so a
// deep load pipeline fits under the 128-VGPR cap of a 512-thread block.
// ---------------------------------------------------------------------------
template <bool F32> struct IO;

template <> struct IO<true> {
    using Raw2 = float2;
    static __device__ __forceinline__ Raw2 ldraw2(const void* p, long long idx) {
        return *(const float2*)((const float*)p + idx);
    }
    static __device__ __forceinline__ void cvt2(const Raw2& u, float f[2]) {
        f[0] = u.x; f[1] = u.y;
    }
    static __device__ __forceinline__ void ld4(const void* p, long long idx, float f[4]) {
        const float4 v = *(const float4*)((const float*)p + idx);
        f[0] = v.x; f[1] = v.y; f[2] = v.z; f[3] = v.w;
    }
    static __device__ __forceinline__ float ld1(const void* p, long long idx) {
        return ((const float*)p)[idx];
    }
    static __device__ __forceinline__ void st4(void* p, long long idx, const float f[4]) {
        *(float4*)((float*)p + idx) = make_float4(f[0], f[1], f[2], f[3]);
    }
    static __device__ __forceinline__ void st4z(void* p, long long idx) {
        *(float4*)((float*)p + idx) = make_float4(0.f, 0.f, 0.f, 0.f);
    }
};

template <> struct IO<false> {
    using Raw2 = uint32_t;
    static __device__ __forceinline__ Raw2 ldraw2(const void* p, long long idx) {
        return *(const uint32_t*)((const uint16_t*)p + idx);
    }
    static __device__ __forceinline__ void cvt2(const Raw2& u, float f[2]) {
        f[0] = bits2f(u << 16);
        f[1] = bits2f(u & 0xFFFF0000u);
    }
    static __device__ __forceinline__ void ld4(const void* p, long long idx, float f[4]) {
        uint2 u = *(const uint2*)((const uint16_t*)p + idx);
        f[0] = bits2f(u.x << 16);
        f[1] = bits2f(u.x & 0xFFFF0000u);
        f[2] = bits2f(u.y << 16);
        f[3] = bits2f(u.y & 0xFFFF0000u);
    }
    static __device__ __forceinline__ float ld1(const void* p, long long idx) {
        return bits2f(((uint32_t)((const uint16_t*)p)[idx]) << 16);
    }
    static __device__ __forceinline__ void st4(void* p, long long idx, const float f[4]) {
        uint2 u;
        u.x = (uint32_t)f2bf(f[0]) | ((uint32_t)f2bf(f[1]) << 16);
        u.y = (uint32_t)f2bf(f[2]) | ((uint32_t)f2bf(f[3]) << 16);
        *(uint2*)((uint16_t*)p + idx) = u;
    }
    static __device__ __forceinline__ void st4z(void* p, long long idx) {
        *(uint2*)((uint16_t*)p + idx) = make_uint2(0u, 0u);
    }
};

__device__ __forceinline__ float sigmoid_f(float x) {
    x = fminf(fmaxf(x, -30.f), 30.f);
    return 1.f / (1.f + __expf(-x));
}
__device__ __forceinline__ float tanh_f(float x) {
    x = fminf(fmaxf(x, -15.f), 15.f);
    float e = __expf(-2.f * x);
    return (1.f - e) / (1.f + e);
}

// ---------------------------------------------------------------------------
// Kernel 1: fill all_hidden_states[:, :, 256:512] with masked tree/graph
// broadcast (zeros at t >= len). 8 elements / thread.
// ---------------------------------------------------------------------------
template <bool F32>
__global__ __launch_bounds__(256) void latent_fill_kernel(
    const void* __restrict__ tree,
    const void* __restrict__ graph,
    const int* __restrict__ lengths,
    const void* __restrict__ Wcs_detect,
    void* __restrict__ out)
{
    __shared__ int s_is32;
    if (threadIdx.x == 0) s_is32 = detect_f32((const uint32_t*)Wcs_detect);
    __syncthreads();
    if ((s_is32 != 0) != F32) return;

    long long idx = (long long)blockIdx.x * 256 + threadIdx.x;   // 0 .. B*T*32
    int c = ((int)(idx & 31)) * 8;           // 0..248 within latent cols
    long long bt = idx >> 5;                 // b*T + t
    int t = (int)(bt % T_N);
    int b = (int)(bt / T_N);

    long long dst = OUT_ALLH + bt * COLS + H_N + c;
    if (t < lengths[b]) {
        float v[8];
        if (c < L_N) {
            IO<F32>::ld4(tree, (long long)b * L_N + c, v);
            IO<F32>::ld4(tree, (long long)b * L_N + c + 4, v + 4);
        } else {
            IO<F32>::ld4(graph, (long long)b * L_N + (c - L_N), v);
            IO<F32>::ld4(graph, (long long)b * L_N + (c - L_N) + 4, v + 4);
        }
        IO<F32>::st4(out, dst, v);
        IO<F32>::st4(out, dst + 4, v + 4);
    } else {
        IO<F32>::st4z(out, dst);
        IO<F32>::st4z(out, dst + 4);
    }
}

// ---------------------------------------------------------------------------
// Kernel 2: k-split block-GEMM GRU, 128-VGPR-fitting load pipeline.
//   512 threads: GEMM role = (kq = tid>>7 in 0..3) x (128 col-threads,
//   2 cols each); gate role = (ro = tid>>6 row-owner) x (64 lanes, 4 cols).
//   A 512-thread block REQUIRES 2 waves/SIMD residency -> hard 128-VGPR cap
//   (r4: exceeding it spilled to scratch, 11.5GB HBM traffic). This layout
//   fits: accumulators az[8][2]+ar[8][2]=32 regs, bf16 weight load for
//   2 cols = one 4B uint = 1 VGPR -> 2x11-deep A/B double-buffer = 44 regs,
//   ~110 total. 22 loads in flight/wave x 2 waves/SIMD hides the ~400cyc
//   L2 latency under each chunk's ~850cyc FMA stream.
//   Math/barriers identical to the verified r2/r3 kernel.
// ---------------------------------------------------------------------------
template <bool F32>
__global__ __launch_bounds__(512, 2) void gru_kernel(
    const void* __restrict__ x_seq,
    const void* __restrict__ hidden,
    const void* __restrict__ graph,
    const int* __restrict__ lengths,
    const void* __restrict__ Wcs, const void* __restrict__ bcs,
    const void* __restrict__ Wz,  const void* __restrict__ bz,
    const void* __restrict__ Wr,  const void* __restrict__ br,
    const void* __restrict__ Wh,  const void* __restrict__ bh,
    void* __restrict__ out)
{
    extern __shared__ float smem[];
    float* Pz  = smem;                      // [NKQ][RB][H_N]
    float* Pr  = Pz  + NKQ * RB * H_N;      // [NKQ][RB][H_N]
    float* xhT = Pr  + NKQ * RB * H_N;      // [KPAD][RB]  (k<5: x, k>=5: h)
    float* xgT = xhT + KPAD * RB;           // [KPAD][RB]  (k<5: x, k>=5: r*h)

    __shared__ int s_is32;
    __shared__ int s_len[RB];
    if (threadIdx.x == 0) s_is32 = detect_f32((const uint32_t*)Wcs);
    __syncthreads();
    if ((s_is32 != 0) != F32) return;

    const int tid  = threadIdx.x;
    const int lane = tid & 63;
    const int kq   = tid >> 7;       // k-group (uniform per wave-pair)
    const int c0   = (tid & 127) * 2;  // GEMM: this thread's 2 columns
    const int ro   = tid >> 6;       // gate: row owner (0..7)
    const int c0g  = lane * 4;       // gate: this thread's 4 columns

    if (tid < RB) {
        int L = lengths[blockIdx.x * RB + tid];
        s_len[tid] = min(max(L, 1), T_N);
    }
    // zero the padded h-rows 261..263 once
    if (tid < (KPAD - KXH) * RB) {
        int p = tid / RB, r = tid - p * RB;
        xhT[(KXH + p) * RB + r] = 0.f;
        xgT[(KXH + p) * RB + r] = 0.f;
    }
    __syncthreads();

    const int b0  = blockIdx.x * RB;
    const int bo  = b0 + ro;                 // owner batch row
    const int len = s_len[ro];
    int maxlen = 1;
    #pragma unroll
    for (int i = 0; i < RB; ++i) maxlen = max(maxlen, s_len[i]);

    // ---- stage [hidden, graph] into Pz region (alias), stride 388 ----
    {
        float* cs = Pz;
        for (int i = tid; i < RB * KCS; i += 512) {
            int r = i / KCS;
            int k = i - r * KCS;
            int bb = b0 + r;
            float v = (k < H_N) ? IO<F32>::ld1(hidden, (long long)bb * H_N + k)
                                : IO<F32>::ld1(graph,  (long long)bb * L_N + (k - H_N));
            cs[r * 388 + k] = v;
        }
    }
    __syncthreads();

    // ---- h0 = relu(cs[ro] @ Wcs + bcs): owner computes its row, full K ----
    float h[4];
    {
        const float* cs = Pz;
        float acc[4];
        IO<F32>::ld4(bcs, c0g, acc);
        for (int k = 0; k < KCS; k += 4) {
            const float4 hv = *reinterpret_cast<const float4*>(&cs[ro * 388 + k]);
            float hvv[4] = {hv.x, hv.y, hv.z, hv.w};
            #pragma unroll
            for (int kk = 0; kk < 4; ++kk) {
                float w[4];
                IO<F32>::ld4(Wcs, (long long)(k + kk) * H_N + c0g, w);
                #pragma unroll
                for (int j = 0; j < 4; ++j) acc[j] += hvv[kk] * w[j];
            }
        }
        #pragma unroll
        for (int j = 0; j < 4; ++j) h[j] = fmaxf(acc[j], 0.f);
    }
    __syncthreads();   // all cs reads done before Pz is reused as partials

    // ---- biases (owner registers, loop-invariant) ----
    float bzv[4], brv[4], bhv[4];
    IO<F32>::ld4(bz, c0g, bzv);
    IO<F32>::ld4(br, c0g, brv);
    IO<F32>::ld4(bh, c0g, bhv);

    float smax[4] = {-1e30f, -1e30f, -1e30f, -1e30f};

    // ---- x prefetch: threads 0..39 own one (row, nuc) slot each ----
    const int xr = tid / NV_N;
    const int xi = tid - xr * NV_N;
    float xv = 0.f;
    if (tid < RB * NV_N)
        xv = IO<F32>::ld1(x_seq, ((long long)(b0 + xr) * T_N + 0) * NV_N + xi);

    // ---- init xhT/xgT: x(0) part + h0 part ----
    if (tid < RB * NV_N) {
        xhT[xi * RB + xr] = xv;
        xgT[xi * RB + xr] = xv;
    }
    #pragma unroll
    for (int j = 0; j < 4; ++j)
        xhT[(NV_N + c0g + j) * RB + ro] = h[j];
    if (tid < RB * NV_N) {
        int tn = (1 < T_N) ? 1 : 0;
        xv = IO<F32>::ld1(x_seq, ((long long)(b0 + xr) * T_N + tn) * NV_N + xi);
    }
    __syncthreads();

    const int k0 = kq * KQ_LEN;

    float z[4];   // persists pass1 -> update

    // raw load double-buffers (1 VGPR each on the bf16 path)
    typename IO<F32>::Raw2 rzA[CH], rrA[CH], rzB[CH], rrB[CH];
    typename IO<F32>::Raw2 rhA[CH], rhB[CH];

#define P1_ISSUE(CHN, RZ, RR)                                               \
    { const int kb_ = k0 + (CHN) * CH;                                      \
      _Pragma("unroll")                                                     \
      for (int i_ = 0; i_ < CH; ++i_) {                                     \
          const int k_  = kb_ + i_;                                         \
          const int kl_ = (k_ <= KXH - 1) ? k_ : (KXH - 1);                 \
          RZ[i_] = IO<F32>::ldraw2(Wz, (long long)kl_ * H_N + c0);          \
          RR[i_] = IO<F32>::ldraw2(Wr, (long long)kl_ * H_N + c0);          \
      } }

#define P1_CONSUME(CHN, RZ, RR)                                             \
    { const int kb_ = k0 + (CHN) * CH;                                      \
      _Pragma("unroll")                                                     \
      for (int i_ = 0; i_ < CH; ++i_) {                                     \
          const int k_ = kb_ + i_;                                          \
          const float4 a4_ = *reinterpret_cast<const float4*>(&xhT[k_ * RB + 0]); \
          const float4 b4_ = *reinterpret_cast<const float4*>(&xhT[k_ * RB + 4]); \
          float hv_[8] = {a4_.x, a4_.y, a4_.z, a4_.w, b4_.x, b4_.y, b4_.z, b4_.w}; \
          float wz2_[2], wr2_[2];                                           \
          IO<F32>::cvt2(RZ[i_], wz2_);                                      \
          IO<F32>::cvt2(RR[i_], wr2_);                                      \
          _Pragma("unroll")                                                 \
          for (int r_ = 0; r_ < 8; ++r_) {                                  \
              az[r_][0] += hv_[r_] * wz2_[0];                               \
              az[r_][1] += hv_[r_] * wz2_[1];                               \
              ar[r_][0] += hv_[r_] * wr2_[0];                               \
              ar[r_][1] += hv_[r_] * wr2_[1];                               \
          } } }

#define P2_ISSUE(CHN, RH)                                                   \
    { const int kb_ = k0 + (CHN) * CH;                                      \
      _Pragma("unroll")                                                     \
      for (int i_ = 0; i_ < CH; ++i_) {                                     \
          const int k_  = kb_ + i_;                                         \
          const int kl_ = (k_ <= KXH - 1) ? k_ : (KXH - 1);                 \
          RH[i_] = IO<F32>::ldraw2(Wh, (long long)kl_ * H_N + c0);          \
      } }

#define P2_CONSUME(CHN, RH)                                                 \
    { const int kb_ = k0 + (CHN) * CH;                                      \
      _Pragma("unroll")                                                     \
      for (int i_ = 0; i_ < CH; ++i_) {                                     \
          const int k_ = kb_ + i_;                                          \
          const float4 a4_ = *reinterpret_cast<const float4*>(&xgT[k_ * RB + 0]); \
          const float4 b4_ = *reinterpret_cast<const float4*>(&xgT[k_ * RB + 4]); \
          float gv_[8] = {a4_.x, a4_.y, a4_.z, a4_.w, b4_.x, b4_.y, b4_.z, b4_.w}; \
          float wh2_[2];                                                    \
          IO<F32>::cvt2(RH[i_], wh2_);                                      \
          _Pragma("unroll")                                                 \
          for (int r_ = 0; r_ < 8; ++r_) {                                  \
              ag[r_][0] += gv_[r_] * wh2_[0];                               \
              ag[r_][1] += gv_[r_] * wh2_[1];                               \
          } } }

    // prologue: first step's pass-1 chunk 0 in flight before the loop
    P1_ISSUE(0, rzA, rrA)

    for (int t = 0; t < maxlen; ++t) {
        // ================= pass 1: partial z,r over this wave's k-range ======
        float az[8][2], ar[8][2];
        #pragma unroll
        for (int r = 0; r < 8; ++r) {
            az[r][0] = 0.f; az[r][1] = 0.f;
            ar[r][0] = 0.f; ar[r][1] = 0.f;
        }

        P1_ISSUE(1, rzB, rrB)        // chunk0 already in flight (prologue/B3)
        P1_CONSUME(0, rzA, rrA)
        P1_ISSUE(2, rzA, rrA)
        P1_CONSUME(1, rzB, rrB)
        P1_ISSUE(3, rzB, rrB)
        P1_CONSUME(2, rzA, rrA)
        P1_ISSUE(4, rzA, rrA)
        P1_CONSUME(3, rzB, rrB)
        P1_ISSUE(5, rzB, rrB)
        P1_CONSUME(4, rzA, rrA)
        P1_CONSUME(5, rzB, rrB)

        #pragma unroll
        for (int r = 0; r < 8; ++r) {
            *reinterpret_cast<float2*>(&Pz[(kq * RB + r) * H_N + c0]) =
                make_float2(az[r][0], az[r][1]);
            *reinterpret_cast<float2*>(&Pr[(kq * RB + r) * H_N + c0]) =
                make_float2(ar[r][0], ar[r][1]);
        }
        P2_ISSUE(0, rhA)             // prefetch Wh chunk0 across B1/gates
        __syncthreads();                           // B1

        // ================= gates z,r (owner: row ro, cols c0g..c0g+3) ========
        {
            float sz[4] = {bzv[0], bzv[1], bzv[2], bzv[3]};
            float sr[4] = {brv[0], brv[1], brv[2], brv[3]};
            #pragma unroll
            for (int q = 0; q < NKQ; ++q) {
                const float4 pz = *reinterpret_cast<const float4*>(&Pz[(q * RB + ro) * H_N + c0g]);
                const float4 pr = *reinterpret_cast<const float4*>(&Pr[(q * RB + ro) * H_N + c0g]);
                sz[0] += pz.x; sz[1] += pz.y; sz[2] += pz.z; sz[3] += pz.w;
                sr[0] += pr.x; sr[1] += pr.y; sr[2] += pr.z; sr[3] += pr.w;
            }
            #pragma unroll
            for (int j = 0; j < 4; ++j) {
                z[j] = sigmoid_f(sz[j]);
                float rr = sigmoid_f(sr[j]);
                xgT[(NV_N + c0g + j) * RB + ro] = rr * h[j];
            }
        }
        __syncthreads();                           // B2

        // ================= pass 2: partial candidate-h =======================
        float ag[8][2];
        #pragma unroll
        for (int r = 0; r < 8; ++r) { ag[r][0] = 0.f; ag[r][1] = 0.f; }

        P2_ISSUE(1, rhB)             // chunk0 already in flight (pre-B1)
        P2_CONSUME(0, rhA)
        P2_ISSUE(2, rhA)
        P2_CONSUME(1, rhB)
        P2_ISSUE(3, rhB)
        P2_CONSUME(2, rhA)
        P2_ISSUE(4, rhA)
        P2_CONSUME(3, rhB)
        P2_ISSUE(5, rhB)
        P2_CONSUME(4, rhA)
        P2_CONSUME(5, rhB)

        #pragma unroll
        for (int r = 0; r < 8; ++r)
            *reinterpret_cast<float2*>(&Pz[(kq * RB + r) * H_N + c0]) =
                make_float2(ag[r][0], ag[r][1]);
        P1_ISSUE(0, rzA, rrA)        // prefetch next step's Wz/Wr chunk0
        __syncthreads();                           // B3

        // ================= reduce + update + stores (owner) ==================
        {
            float sg[4] = {bhv[0], bhv[1], bhv[2], bhv[3]};
            #pragma unroll
            for (int q = 0; q < NKQ; ++q) {
                const float4 pg = *reinterpret_cast<const float4*>(&Pz[(q * RB + ro) * H_N + c0g]);
                sg[0] += pg.x; sg[1] += pg.y; sg[2] += pg.z; sg[3] += pg.w;
            }
            const bool active = (t < len);
            float hs[4];
            #pragma unroll
            for (int j = 0; j < 4; ++j) {
                float pre = tanh_f(sg[j]);
                float hn  = (1.f - z[j]) * h[j] + z[j] * pre;
                hn = active ? hn : h[j];
                h[j]  = hn;
                hs[j] = active ? hn : 0.f;
                smax[j] = active ? fmaxf(smax[j], hn) : smax[j];
                xhT[(NV_N + c0g + j) * RB + ro] = hn;
            }
            IO<F32>::st4(out, OUT_ALLH + ((long long)bo * T_N + t) * COLS + c0g, hs);
            if (t == len - 1)
                IO<F32>::st4(out, (long long)bo * H_N + c0g, h);
        }
        // stage x(t+1) and prefetch x(t+2)
        if (tid < RB * NV_N) {
            xhT[xi * RB + xr] = xv;
            xgT[xi * RB + xr] = xv;
            int tn = (t + 2 < T_N) ? (t + 2) : (T_N - 1);
            xv = IO<F32>::ld1(x_seq, ((long long)(b0 + xr) * T_N + tn) * NV_N + xi);
        }
        __syncthreads();                           // B4
    }

#undef P1_ISSUE
#undef P1_CONSUME
#undef P2_ISSUE
#undef P2_CONSUME

    // zero-fill all_h h-columns for t >= maxlen (rows with len<maxlen got
    // zeros in-loop); harness poisons d_out so every element must be written
    for (int t = maxlen; t < T_N; ++t)
        IO<F32>::st4z(out, OUT_ALLH + ((long long)bo * T_N + t) * COLS + c0g);

    IO<F32>::st4(out, OUT_SEG + (long long)bo * H_N + c0g, smax);
}

extern "C" void kernel_launch(void* const* d_in, const int* in_sizes, int n_in,
                              void* d_out, int out_size, void* d_ws, size_t ws_size,
                              hipStream_t stream) {
    const void* x_seq  = d_in[0];
    const void* hidden = d_in[1];
    const void* tree   = d_in[2];
    const void* graph  = d_in[3];
    const int*  lens   = (const int*)d_in[4];
    const void* Wcs    = d_in[5];
    const void* bcs    = d_in[6];
    const void* Wz     = d_in[7];
    const void* bz     = d_in[8];
    const void* Wr     = d_in[9];
    const void* br     = d_in[10];
    const void* Wh     = d_in[11];
    const void* bh     = d_in[12];
    void* out = d_out;

    // allow >64KB dynamic LDS (once per process; host-side, capture-safe)
    static bool attr_set = false;
    if (!attr_set) {
        (void)hipFuncSetAttribute(reinterpret_cast<const void*>(&gru_kernel<true>),
                                  hipFuncAttributeMaxDynamicSharedMemorySize, SMEM_BYTES);
        (void)hipFuncSetAttribute(reinterpret_cast<const void*>(&gru_kernel<false>),
                                  hipFuncAttributeMaxDynamicSharedMemorySize, SMEM_BYTES);
        attr_set = true;
    }

    long long work = (long long)B_N * T_N * 32;
    int fill_blocks = (int)(work / 256);   // 25600

    // Launch BOTH dtype variants; each self-selects via detect_f32 and the
    // mismatching variant exits immediately. Deterministic work per call
    // => graph-capture safe.
    hipLaunchKernelGGL((latent_fill_kernel<true>),  dim3(fill_blocks), dim3(256), 0, stream,
                       tree, graph, lens, Wcs, out);
    hipLaunchKernelGGL((latent_fill_kernel<false>), dim3(fill_blocks), dim3(256), 0, stream,
                       tree, graph, lens, Wcs, out);

    hipLaunchKernelGGL((gru_kernel<true>), dim3(B_N / RB), dim3(512), SMEM_BYTES, stream,
                       x_seq, hidden, graph, lens,
                       Wcs, bcs, Wz, bz, Wr, br, Wh, bh, out);
    hipLaunchKernelGGL((gru_kernel<false>), dim3(B_N / RB), dim3(512), SMEM_BYTES, stream,
                       x_seq, hidden, graph, lens,
                       Wcs, bcs, Wz, bz, Wr, br, Wh, bh, out);
}

// Round 8
// 4127.023 us; speedup vs baseline: 2.2080x; 2.2080x over previous
//
#include <hip/hip_runtime.h>
#include <stdint.h>

// Problem constants (from reference)
#define B_N 2048
#define T_N 100
#define H_N 256
#define L_N 128
#define NV_N 5
#define COLS 512               // columns of all_hidden_states

#define KCS 384                // H + L rows of Wcs
#define RB 8                   // batch rows per block
#define NKQ 2                  // k-split groups (2 waves each)
#define KQH 128                // h-rows per k-group
#define CH 16                  // k-rows per chunk
#define NCH 8                  // chunks per pass per k-group (128/16)
#define HSTR 264               // hstage row stride: h[0..255], x[256..260], pad

// Output element offsets, concatenated in return order:
// new_h [B,H], all_hidden_states [B,T,512], seg_rep [B,H]
static constexpr long long OUT_ALLH = (long long)B_N * H_N;                     // 524288
static constexpr long long OUT_SEG  = OUT_ALLH + (long long)B_N * T_N * COLS;   // 105381888

__device__ __forceinline__ float bits2f(uint32_t u) {
    union { uint32_t u; float f; } v; v.u = u; return v.f;
}
__device__ __forceinline__ uint16_t f2bf(float f) {
    union { float f; uint32_t u; } v; v.f = f;
    uint32_t r = (v.u + 0x7FFFu + ((v.u >> 16) & 1u)) >> 16;   // round-nearest-even
    return (uint16_t)r;
}

// ---------------------------------------------------------------------------
// Runtime dtype detection (unchanged, verified): majority vote on the
// fp32-exponent field of 64 words of W_cs.
// ---------------------------------------------------------------------------
__device__ __forceinline__ int detect_f32(const uint32_t* __restrict__ w) {
    int cnt = 0;
    #pragma unroll 8
    for (int i = 0; i < 64; ++i) {
        uint32_t e = (w[i] >> 23) & 0xFFu;
        cnt += (e >= 97u && e <= 130u) ? 1 : 0;
    }
    return cnt >= 32 ? 1 : 0;
}

// ---------------------------------------------------------------------------
// Dtype-abstracted element access. Index units are ELEMENTS.
// Raw2/ldraw2/cvt2: 2-element raw load (bf16: one 4B uint = 1 VGPR) so the
// load pipeline fits the register budget.
// ---------------------------------------------------------------------------
template <bool F32> struct IO;

template <> struct IO<true> {
    using Raw2 = float2;
    static __device__ __forceinline__ Raw2 ldraw2(const void* p, long long idx) {
        return *(const float2*)((const float*)p + idx);
    }
    static __device__ __forceinline__ void cvt2(const Raw2& u, float f[2]) {
        f[0] = u.x; f[1] = u.y;
    }
    static __device__ __forceinline__ void ld4(const void* p, long long idx, float f[4]) {
        const float4 v = *(const float4*)((const float*)p + idx);
        f[0] = v.x; f[1] = v.y; f[2] = v.z; f[3] = v.w;
    }
    static __device__ __forceinline__ float ld1(const void* p, long long idx) {
        return ((const float*)p)[idx];
    }
    static __device__ __forceinline__ void st4(void* p, long long idx, const float f[4]) {
        *(float4*)((float*)p + idx) = make_float4(f[0], f[1], f[2], f[3]);
    }
    static __device__ __forceinline__ void st4z(void* p, long long idx) {
        *(float4*)((float*)p + idx) = make_float4(0.f, 0.f, 0.f, 0.f);
    }
};

template <> struct IO<false> {
    using Raw2 = uint32_t;
    static __device__ __forceinline__ Raw2 ldraw2(const void* p, long long idx) {
        return *(const uint32_t*)((const uint16_t*)p + idx);
    }
    static __device__ __forceinline__ void cvt2(const Raw2& u, float f[2]) {
        f[0] = bits2f(u << 16);
        f[1] = bits2f(u & 0xFFFF0000u);
    }
    static __device__ __forceinline__ void ld4(const void* p, long long idx, float f[4]) {
        uint2 u = *(const uint2*)((const uint16_t*)p + idx);
        f[0] = bits2f(u.x << 16);
        f[1] = bits2f(u.x & 0xFFFF0000u);
        f[2] = bits2f(u.y << 16);
        f[3] = bits2f(u.y & 0xFFFF0000u);
    }
    static __device__ __forceinline__ float ld1(const void* p, long long idx) {
        return bits2f(((uint32_t)((const uint16_t*)p)[idx]) << 16);
    }
    static __device__ __forceinline__ void st4(void* p, long long idx, const float f[4]) {
        uint2 u;
        u.x = (uint32_t)f2bf(f[0]) | ((uint32_t)f2bf(f[1]) << 16);
        u.y = (uint32_t)f2bf(f[2]) | ((uint32_t)f2bf(f[3]) << 16);
        *(uint2*)((uint16_t*)p + idx) = u;
    }
    static __device__ __forceinline__ void st4z(void* p, long long idx) {
        *(uint2*)((uint16_t*)p + idx) = make_uint2(0u, 0u);
    }
};

__device__ __forceinline__ float sigmoid_f(float x) {
    x = fminf(fmaxf(x, -30.f), 30.f);
    return 1.f / (1.f + __expf(-x));
}
__device__ __forceinline__ float tanh_f(float x) {
    x = fminf(fmaxf(x, -15.f), 15.f);
    float e = __expf(-2.f * x);
    return (1.f - e) / (1.f + e);
}

// ---------------------------------------------------------------------------
// Kernel 1: fill all_hidden_states[:, :, 256:512] with masked tree/graph
// broadcast (zeros at t >= len). 8 elements / thread. Unchanged.
// ---------------------------------------------------------------------------
template <bool F32>
__global__ __launch_bounds__(256) void latent_fill_kernel(
    const void* __restrict__ tree,
    const void* __restrict__ graph,
    const int* __restrict__ lengths,
    const void* __restrict__ Wcs_detect,
    void* __restrict__ out)
{
    __shared__ int s_is32;
    if (threadIdx.x == 0) s_is32 = detect_f32((const uint32_t*)Wcs_detect);
    __syncthreads();
    if ((s_is32 != 0) != F32) return;

    long long idx = (long long)blockIdx.x * 256 + threadIdx.x;   // 0 .. B*T*32
    int c = ((int)(idx & 31)) * 8;           // 0..248 within latent cols
    long long bt = idx >> 5;                 // b*T + t
    int t = (int)(bt % T_N);
    int b = (int)(bt / T_N);

    long long dst = OUT_ALLH + bt * COLS + H_N + c;
    if (t < lengths[b]) {
        float v[8];
        if (c < L_N) {
            IO<F32>::ld4(tree, (long long)b * L_N + c, v);
            IO<F32>::ld4(tree, (long long)b * L_N + c + 4, v + 4);
        } else {
            IO<F32>::ld4(graph, (long long)b * L_N + (c - L_N), v);
            IO<F32>::ld4(graph, (long long)b * L_N + (c - L_N) + 4, v + 4);
        }
        IO<F32>::st4(out, dst, v);
        IO<F32>::st4(out, dst + 4, v + 4);
    } else {
        IO<F32>::st4z(out, dst);
        IO<F32>::st4z(out, dst + 4);
    }
}

// ---------------------------------------------------------------------------
// Kernel 2: k-split block-GEMM GRU, 256-thread / 256-VGPR-budget pipeline.
//   256 threads = 4 waves = 1 wave/SIMD -> per-wave VGPR budget 256 (the
//   r2-r5 versions used 512-thread blocks whose hard 128-VGPR cap either
//   serialized the load pipeline (r2/r3) or spilled it (r4/r5: 11.5GB
//   scratch traffic)). Latency hiding now comes from ILP: 16-k chunks,
//   A/B double-buffered, 32 weight loads in flight per wave.
//   GEMM role: kq = tid>>7 (2 k-groups x 128 h-rows), 2 cols/thread.
//   Gate role: ro = tid>>5 (8 row-owners), 8 cols/thread.
//   h lives ROW-MAJOR in hstage[r][0..255] (+x at [256..260]): gate-phase
//   writes are contiguous float4s (kills the 32-way transposed-write bank
//   conflict of r2-r5 = 1.23e8 cycles); GEMM-phase reads are same-address
//   float2 broadcasts (conflict-free).
// ---------------------------------------------------------------------------
template <bool F32>
__global__ __launch_bounds__(256, 1) void gru_kernel(
    const void* __restrict__ x_seq,
    const void* __restrict__ hidden,
    const void* __restrict__ graph,
    const int* __restrict__ lengths,
    const void* __restrict__ Wcs, const void* __restrict__ bcs,
    const void* __restrict__ Wz,  const void* __restrict__ bz,
    const void* __restrict__ Wr,  const void* __restrict__ br,
    const void* __restrict__ Wh,  const void* __restrict__ bh,
    void* __restrict__ out)
{
    __shared__ float Pz[NKQ][RB][H_N];       // 16 KB  (aliased as cs at init)
    __shared__ float Pr[NKQ][RB][H_N];       // 16 KB
    __shared__ float hstage[RB][HSTR];       // 8.25 KB  [r][k]: h, then x
    __shared__ float gstage[RB][HSTR];       // 8.25 KB  [r][k]: r*h, then x
    __shared__ int s_is32;
    __shared__ int s_len[RB];

    if (threadIdx.x == 0) s_is32 = detect_f32((const uint32_t*)Wcs);
    __syncthreads();
    if ((s_is32 != 0) != F32) return;

    const int tid = threadIdx.x;
    const int kq  = tid >> 7;          // k-group (wave-pair uniform)
    const int c0  = (tid & 127) * 2;   // GEMM: this thread's 2 columns
    const int ro  = tid >> 5;          // gate: row owner (0..7)
    const int c0g = (tid & 31) * 8;    // gate: this thread's 8 columns
    const int kh0 = kq * KQH;          // first h-row of this k-group

    if (tid < RB) {
        int L = lengths[blockIdx.x * RB + tid];
        s_len[tid] = min(max(L, 1), T_N);
    }
    __syncthreads();

    const int b0  = blockIdx.x * RB;
    const int bo  = b0 + ro;           // owner batch row
    const int len = s_len[ro];
    int maxlen = 1;
    #pragma unroll
    for (int i = 0; i < RB; ++i) maxlen = max(maxlen, s_len[i]);

    // ---- stage [hidden, graph] into Pz alias (stride 388) ----
    {
        float* cs = &Pz[0][0][0];
        for (int i = tid; i < RB * KCS; i += 256) {
            int r = i / KCS;
            int k = i - r * KCS;
            int bb = b0 + r;
            float v = (k < H_N) ? IO<F32>::ld1(hidden, (long long)bb * H_N + k)
                                : IO<F32>::ld1(graph,  (long long)bb * L_N + (k - H_N));
            cs[r * 388 + k] = v;
        }
    }
    __syncthreads();

    // ---- h0 = relu(cs[ro] @ Wcs + bcs): gate layout, 8 cols/thread ----
    float h[8];
    {
        const float* cs = &Pz[0][0][0];
        float acc[8];
        IO<F32>::ld4(bcs, c0g, acc);
        IO<F32>::ld4(bcs, c0g + 4, acc + 4);
        for (int k = 0; k < KCS; k += 4) {
            const float4 hv = *reinterpret_cast<const float4*>(&cs[ro * 388 + k]);
            const float hvv[4] = {hv.x, hv.y, hv.z, hv.w};
            #pragma unroll
            for (int kk = 0; kk < 4; ++kk) {
                float w[8];
                IO<F32>::ld4(Wcs, (long long)(k + kk) * H_N + c0g, w);
                IO<F32>::ld4(Wcs, (long long)(k + kk) * H_N + c0g + 4, w + 4);
                #pragma unroll
                for (int j = 0; j < 8; ++j) acc[j] += hvv[kk] * w[j];
            }
        }
        #pragma unroll
        for (int j = 0; j < 8; ++j) h[j] = fmaxf(acc[j], 0.f);
    }

    // ---- biases (gate layout, loop-invariant) ----
    float bzv[8], brv[8], bhv[8];
    IO<F32>::ld4(bz, c0g, bzv); IO<F32>::ld4(bz, c0g + 4, bzv + 4);
    IO<F32>::ld4(br, c0g, brv); IO<F32>::ld4(br, c0g + 4, brv + 4);
    IO<F32>::ld4(bh, c0g, bhv); IO<F32>::ld4(bh, c0g + 4, bhv + 4);

    float smax[8];
    #pragma unroll
    for (int j = 0; j < 8; ++j) smax[j] = -1e30f;

    __syncthreads();   // all cs reads done (Pz free for partials)

    // ---- h0 -> hstage; x(0) -> hstage/gstage; prefetch x(1) ----
    *reinterpret_cast<float4*>(&hstage[ro][c0g])     = make_float4(h[0], h[1], h[2], h[3]);
    *reinterpret_cast<float4*>(&hstage[ro][c0g + 4]) = make_float4(h[4], h[5], h[6], h[7]);

    const int xr = tid / NV_N;
    const int xi = tid - xr * NV_N;
    float xv = 0.f;
    if (tid < RB * NV_N) {
        float x0 = IO<F32>::ld1(x_seq, ((long long)(b0 + xr) * T_N + 0) * NV_N + xi);
        hstage[xr][H_N + xi] = x0;
        gstage[xr][H_N + xi] = x0;
        int tn = (1 < T_N) ? 1 : 0;
        xv = IO<F32>::ld1(x_seq, ((long long)(b0 + xr) * T_N + tn) * NV_N + xi);
    }
    __syncthreads();

    float z[8];   // persists gates -> update

    // raw load buffers (bf16: 1 VGPR each)
    typename IO<F32>::Raw2 zA[CH], rA[CH], zB[CH], rB[CH], hA[CH], hB[CH];
    typename IO<F32>::Raw2 xzb[NV_N], xrb[NV_N], xhb[NV_N];

#define P1_ISSUE(CHN, RZ, RR) { \
    const int kb_ = 5 + kh0 + (CHN) * CH; \
    _Pragma("unroll") \
    for (int i_ = 0; i_ < CH; ++i_) { \
        RZ[i_] = IO<F32>::ldraw2(Wz, (long long)(kb_ + i_) * H_N + c0); \
        RR[i_] = IO<F32>::ldraw2(Wr, (long long)(kb_ + i_) * H_N + c0); \
    } \
    __builtin_amdgcn_sched_barrier(0); }

#define P1_CONSUME(CHN, RZ, RR) { \
    const int kb_ = kh0 + (CHN) * CH; \
    _Pragma("unroll") \
    for (int g_ = 0; g_ < CH / 2; ++g_) { \
        float2 hr_[RB]; \
        _Pragma("unroll") \
        for (int r_ = 0; r_ < RB; ++r_) \
            hr_[r_] = *reinterpret_cast<const float2*>(&hstage[r_][kb_ + 2 * g_]); \
        _Pragma("unroll") \
        for (int u_ = 0; u_ < 2; ++u_) { \
            float wz2_[2], wr2_[2]; \
            IO<F32>::cvt2(RZ[2 * g_ + u_], wz2_); \
            IO<F32>::cvt2(RR[2 * g_ + u_], wr2_); \
            _Pragma("unroll") \
            for (int r_ = 0; r_ < RB; ++r_) { \
                const float hv_ = u_ ? hr_[r_].y : hr_[r_].x; \
                az[r_][0] += hv_ * wz2_[0]; \
                az[r_][1] += hv_ * wz2_[1]; \
                ar[r_][0] += hv_ * wr2_[0]; \
                ar[r_][1] += hv_ * wr2_[1]; \
            } } } }

#define P2_ISSUE(CHN, RH) { \
    const int kb_ = 5 + kh0 + (CHN) * CH; \
    _Pragma("unroll") \
    for (int i_ = 0; i_ < CH; ++i_) \
        RH[i_] = IO<F32>::ldraw2(Wh, (long long)(kb_ + i_) * H_N + c0); \
    __builtin_amdgcn_sched_barrier(0); }

#define P2_CONSUME(CHN, RH) { \
    const int kb_ = kh0 + (CHN) * CH; \
    _Pragma("unroll") \
    for (int g_ = 0; g_ < CH / 2; ++g_) { \
        float2 gr_[RB]; \
        _Pragma("unroll") \
        for (int r_ = 0; r_ < RB; ++r_) \
            gr_[r_] = *reinterpret_cast<const float2*>(&gstage[r_][kb_ + 2 * g_]); \
        _Pragma("unroll") \
        for (int u_ = 0; u_ < 2; ++u_) { \
            float wh2_[2]; \
            IO<F32>::cvt2(RH[2 * g_ + u_], wh2_); \
            _Pragma("unroll") \
            for (int r_ = 0; r_ < RB; ++r_) { \
                const float gv_ = u_ ? gr_[r_].y : gr_[r_].x; \
                ag[r_][0] += gv_ * wh2_[0]; \
                ag[r_][1] += gv_ * wh2_[1]; \
            } } } }

#define PX_ISSUE() if (kq == 0) { \
    _Pragma("unroll") \
    for (int i_ = 0; i_ < NV_N; ++i_) { \
        xzb[i_] = IO<F32>::ldraw2(Wz, (long long)i_ * H_N + c0); \
        xrb[i_] = IO<F32>::ldraw2(Wr, (long long)i_ * H_N + c0); \
    } }

#define PXH_ISSUE() if (kq == 0) { \
    _Pragma("unroll") \
    for (int i_ = 0; i_ < NV_N; ++i_) \
        xhb[i_] = IO<F32>::ldraw2(Wh, (long long)i_ * H_N + c0); }

#define P1X_CONSUME() if (kq == 0) { \
    _Pragma("unroll") \
    for (int i_ = 0; i_ < NV_N; ++i_) { \
        float wz2_[2], wr2_[2]; \
        IO<F32>::cvt2(xzb[i_], wz2_); \
        IO<F32>::cvt2(xrb[i_], wr2_); \
        _Pragma("unroll") \
        for (int r_ = 0; r_ < RB; ++r_) { \
            const float xv_ = hstage[r_][H_N + i_]; \
            az[r_][0] += xv_ * wz2_[0]; \
            az[r_][1] += xv_ * wz2_[1]; \
            ar[r_][0] += xv_ * wr2_[0]; \
            ar[r_][1] += xv_ * wr2_[1]; \
        } } }

#define P2X_CONSUME() if (kq == 0) { \
    _Pragma("unroll") \
    for (int i_ = 0; i_ < NV_N; ++i_) { \
        float wh2_[2]; \
        IO<F32>::cvt2(xhb[i_], wh2_); \
        _Pragma("unroll") \
        for (int r_ = 0; r_ < RB; ++r_) { \
            const float xv_ = gstage[r_][H_N + i_]; \
            ag[r_][0] += xv_ * wh2_[0]; \
            ag[r_][1] += xv_ * wh2_[1]; \
        } } }

    // prologue: first step's pass-1 chunk 0 + x-part in flight
    PX_ISSUE();
    P1_ISSUE(0, zA, rA);

    #pragma unroll 1
    for (int t = 0; t < maxlen; ++t) {
        // ===== pass 1: partial z,r over this k-group =====
        float az[RB][2], ar[RB][2];
        #pragma unroll
        for (int r = 0; r < RB; ++r) {
            az[r][0] = 0.f; az[r][1] = 0.f;
            ar[r][0] = 0.f; ar[r][1] = 0.f;
        }
        #pragma unroll 1
        for (int ch = 0; ch < NCH; ch += 2) {
            P1_ISSUE(ch + 1, zB, rB);
            P1_CONSUME(ch, zA, rA);
            if (ch + 2 < NCH) { P1_ISSUE(ch + 2, zA, rA); }
            else              { P2_ISSUE(0, hA); PXH_ISSUE(); }
            P1_CONSUME(ch + 1, zB, rB);
        }
        P1X_CONSUME();
        #pragma unroll
        for (int r = 0; r < RB; ++r) {
            *reinterpret_cast<float2*>(&Pz[kq][r][c0]) = make_float2(az[r][0], az[r][1]);
            *reinterpret_cast<float2*>(&Pr[kq][r][c0]) = make_float2(ar[r][0], ar[r][1]);
        }
        __syncthreads();                           // B1

        // ===== gates z,r (owner: row ro, cols c0g..c0g+7) =====
        {
            float sz[8], sr[8];
            #pragma unroll
            for (int j = 0; j < 8; ++j) { sz[j] = bzv[j]; sr[j] = brv[j]; }
            #pragma unroll
            for (int q = 0; q < NKQ; ++q) {
                float4 a = *reinterpret_cast<const float4*>(&Pz[q][ro][c0g]);
                float4 b = *reinterpret_cast<const float4*>(&Pz[q][ro][c0g + 4]);
                sz[0] += a.x; sz[1] += a.y; sz[2] += a.z; sz[3] += a.w;
                sz[4] += b.x; sz[5] += b.y; sz[6] += b.z; sz[7] += b.w;
                a = *reinterpret_cast<const float4*>(&Pr[q][ro][c0g]);
                b = *reinterpret_cast<const float4*>(&Pr[q][ro][c0g + 4]);
                sr[0] += a.x; sr[1] += a.y; sr[2] += a.z; sr[3] += a.w;
                sr[4] += b.x; sr[5] += b.y; sr[6] += b.z; sr[7] += b.w;
            }
            float rh[8];
            #pragma unroll
            for (int j = 0; j < 8; ++j) {
                z[j] = sigmoid_f(sz[j]);
                rh[j] = sigmoid_f(sr[j]) * h[j];
            }
            *reinterpret_cast<float4*>(&gstage[ro][c0g])     = make_float4(rh[0], rh[1], rh[2], rh[3]);
            *reinterpret_cast<float4*>(&gstage[ro][c0g + 4]) = make_float4(rh[4], rh[5], rh[6], rh[7]);
        }
        __syncthreads();                           // B2

        // ===== pass 2: partial candidate-h =====
        float ag[RB][2];
        #pragma unroll
        for (int r = 0; r < RB; ++r) { ag[r][0] = 0.f; ag[r][1] = 0.f; }
        #pragma unroll 1
        for (int ch = 0; ch < NCH; ch += 2) {
            P2_ISSUE(ch + 1, hB);
            P2_CONSUME(ch, hA);
            if (ch + 2 < NCH) { P2_ISSUE(ch + 2, hA); }
            else              { P1_ISSUE(0, zA, rA); PX_ISSUE(); }   // next step
            P2_CONSUME(ch + 1, hB);
        }
        P2X_CONSUME();
        #pragma unroll
        for (int r = 0; r < RB; ++r)
            *reinterpret_cast<float2*>(&Pz[kq][r][c0]) = make_float2(ag[r][0], ag[r][1]);
        __syncthreads();                           // B3

        // ===== reduce + update + stores (owner) =====
        {
            float sg[8];
            #pragma unroll
            for (int j = 0; j < 8; ++j) sg[j] = bhv[j];
            #pragma unroll
            for (int q = 0; q < NKQ; ++q) {
                float4 a = *reinterpret_cast<const float4*>(&Pz[q][ro][c0g]);
                float4 b = *reinterpret_cast<const float4*>(&Pz[q][ro][c0g + 4]);
                sg[0] += a.x; sg[1] += a.y; sg[2] += a.z; sg[3] += a.w;
                sg[4] += b.x; sg[5] += b.y; sg[6] += b.z; sg[7] += b.w;
            }
            const bool active = (t < len);
            float hs[8];
            #pragma unroll
            for (int j = 0; j < 8; ++j) {
                float pre = tanh_f(sg[j]);
                float hn  = (1.f - z[j]) * h[j] + z[j] * pre;
                hn = active ? hn : h[j];
                h[j]  = hn;
                hs[j] = active ? hn : 0.f;
                smax[j] = active ? fmaxf(smax[j], hn) : smax[j];
            }
            IO<F32>::st4(out, OUT_ALLH + ((long long)bo * T_N + t) * COLS + c0g, hs);
            IO<F32>::st4(out, OUT_ALLH + ((long long)bo * T_N + t) * COLS + c0g + 4, hs + 4);
            if (t == len - 1) {
                IO<F32>::st4(out, (long long)bo * H_N + c0g, h);
                IO<F32>::st4(out, (long long)bo * H_N + c0g + 4, h + 4);
            }
            *reinterpret_cast<float4*>(&hstage[ro][c0g])     = make_float4(h[0], h[1], h[2], h[3]);
            *reinterpret_cast<float4*>(&hstage[ro][c0g + 4]) = make_float4(h[4], h[5], h[6], h[7]);
        }
        // stage x(t+1), prefetch x(t+2)
        if (tid < RB * NV_N) {
            hstage[xr][H_N + xi] = xv;
            gstage[xr][H_N + xi] = xv;
            int tn = (t + 2 < T_N) ? (t + 2) : (T_N - 1);
            xv = IO<F32>::ld1(x_seq, ((long long)(b0 + xr) * T_N + tn) * NV_N + xi);
        }
        __syncthreads();                           // B4
    }

#undef P1_ISSUE
#undef P1_CONSUME
#undef P2_ISSUE
#undef P2_CONSUME
#undef PX_ISSUE
#undef PXH_ISSUE
#undef P1X_CONSUME
#undef P2X_CONSUME

    // zero-fill all_h h-columns for t >= maxlen (rows with len<maxlen got
    // zeros in-loop); harness poisons d_out so every element must be written
    for (int t = maxlen; t < T_N; ++t) {
        IO<F32>::st4z(out, OUT_ALLH + ((long long)bo * T_N + t) * COLS + c0g);
        IO<F32>::st4z(out, OUT_ALLH + ((long long)bo * T_N + t) * COLS + c0g + 4);
    }
    IO<F32>::st4(out, OUT_SEG + (long long)bo * H_N + c0g, smax);
    IO<F32>::st4(out, OUT_SEG + (long long)bo * H_N + c0g + 4, smax + 4);
}

extern "C" void kernel_launch(void* const* d_in, const int* in_sizes, int n_in,
                              void* d_out, int out_size, void* d_ws, size_t ws_size,
                              hipStream_t stream) {
    const void* x_seq  = d_in[0];
    const void* hidden = d_in[1];
    const void* tree   = d_in[2];
    const void* graph  = d_in[3];
    const int*  lens   = (const int*)d_in[4];
    const void* Wcs    = d_in[5];
    const void* bcs    = d_in[6];
    const void* Wz     = d_in[7];
    const void* bz     = d_in[8];
    const void* Wr     = d_in[9];
    const void* br     = d_in[10];
    const void* Wh     = d_in[11];
    const void* bh     = d_in[12];
    void* out = d_out;

    long long work = (long long)B_N * T_N * 32;
    int fill_blocks = (int)(work / 256);   // 25600

    // Launch BOTH dtype variants; each self-selects via detect_f32 and the
    // mismatching variant exits immediately. Deterministic work per call
    // => graph-capture safe.
    hipLaunchKernelGGL((latent_fill_kernel<true>),  dim3(fill_blocks), dim3(256), 0, stream,
                       tree, graph, lens, Wcs, out);
    hipLaunchKernelGGL((latent_fill_kernel<false>), dim3(fill_blocks), dim3(256), 0, stream,
                       tree, graph, lens, Wcs, out);

    hipLaunchKernelGGL((gru_kernel<true>), dim3(B_N / RB), dim3(256), 0, stream,
                       x_seq, hidden, graph, lens,
                       Wcs, bcs, Wz, bz, Wr, br, Wh, bh, out);
    hipLaunchKernelGGL((gru_kernel<false>), dim3(B_N / RB), dim3(256), 0, stream,
                       x_seq, hidden, graph, lens,
                       Wcs, bcs, Wz, bz, Wr, br, Wh, bh, out);
}

// Round 9
// 4076.342 us; speedup vs baseline: 2.2354x; 1.0124x over previous
//
#include <hip/hip_runtime.h>
#include <stdint.h>

// Problem constants (from reference)
#define B_N 2048
#define T_N 100
#define H_N 256
#define L_N 128
#define NV_N 5
#define COLS 512               // columns of all_hidden_states

#define KCS 384                // H + L rows of Wcs
#define RB 8                   // batch rows per block
#define NKQ 2                  // k-split groups (2 waves each)
#define KQH 128                // h-rows per k-group
#define CH 16                  // k-rows per chunk
#define NCH 8                  // chunks per pass per k-group (128/16)
#define HSTR 264               // hstage row stride: h[0..255], x[256..260], pad

// Output element offsets, concatenated in return order:
// new_h [B,H], all_hidden_states [B,T,512], seg_rep [B,H]
// Max element index 105,906,175; x4B = 424MB < 2^31 -> 32-bit indexing is
// safe EVERYWHERE (the r8 kernel's long long indices materialized ~2 VGPRs
// of 64-bit address per in-flight load -> blew the 256-VGPR budget -> spill).
static constexpr int OUT_ALLH = B_N * H_N;                     // 524288
static constexpr int OUT_SEG  = OUT_ALLH + B_N * T_N * COLS;   // 105381888

__device__ __forceinline__ float bits2f(uint32_t u) {
    union { uint32_t u; float f; } v; v.u = u; return v.f;
}
__device__ __forceinline__ uint16_t f2bf(float f) {
    union { float f; uint32_t u; } v; v.f = f;
    uint32_t r = (v.u + 0x7FFFu + ((v.u >> 16) & 1u)) >> 16;   // round-nearest-even
    return (uint16_t)r;
}

// ---------------------------------------------------------------------------
// Runtime dtype detection (unchanged, verified): majority vote on the
// fp32-exponent field of 64 words of W_cs.
// ---------------------------------------------------------------------------
__device__ __forceinline__ int detect_f32(const uint32_t* __restrict__ w) {
    int cnt = 0;
    #pragma unroll 8
    for (int i = 0; i < 64; ++i) {
        uint32_t e = (w[i] >> 23) & 0xFFu;
        cnt += (e >= 97u && e <= 130u) ? 1 : 0;
    }
    return cnt >= 32 ? 1 : 0;
}

// ---------------------------------------------------------------------------
// Dtype-abstracted element access. Index units are ELEMENTS, 32-bit int:
// wave-uniform row offsets become SGPRs; the per-lane column offset is one
// shared VGPR -> addressing cost ~2 VGPRs total instead of ~60.
// ---------------------------------------------------------------------------
template <bool F32> struct IO;

template <> struct IO<true> {
    using Raw2 = float2;
    static __device__ __forceinline__ Raw2 ldraw2(const void* p, int idx) {
        return *(const float2*)((const float*)p + idx);
    }
    static __device__ __forceinline__ void cvt2(const Raw2& u, float f[2]) {
        f[0] = u.x; f[1] = u.y;
    }
    static __device__ __forceinline__ void ld4(const void* p, int idx, float f[4]) {
        const float4 v = *(const float4*)((const float*)p + idx);
        f[0] = v.x; f[1] = v.y; f[2] = v.z; f[3] = v.w;
    }
    static __device__ __forceinline__ float ld1(const void* p, int idx) {
        return ((const float*)p)[idx];
    }
    static __device__ __forceinline__ void st4(void* p, int idx, const float f[4]) {
        *(float4*)((float*)p + idx) = make_float4(f[0], f[1], f[2], f[3]);
    }
    static __device__ __forceinline__ void st4z(void* p, int idx) {
        *(float4*)((float*)p + idx) = make_float4(0.f, 0.f, 0.f, 0.f);
    }
};

template <> struct IO<false> {
    using Raw2 = uint32_t;
    static __device__ __forceinline__ Raw2 ldraw2(const void* p, int idx) {
        return *(const uint32_t*)((const uint16_t*)p + idx);
    }
    static __device__ __forceinline__ void cvt2(const Raw2& u, float f[2]) {
        f[0] = bits2f(u << 16);
        f[1] = bits2f(u & 0xFFFF0000u);
    }
    static __device__ __forceinline__ void ld4(const void* p, int idx, float f[4]) {
        uint2 u = *(const uint2*)((const uint16_t*)p + idx);
        f[0] = bits2f(u.x << 16);
        f[1] = bits2f(u.x & 0xFFFF0000u);
        f[2] = bits2f(u.y << 16);
        f[3] = bits2f(u.y & 0xFFFF0000u);
    }
    static __device__ __forceinline__ float ld1(const void* p, int idx) {
        return bits2f(((uint32_t)((const uint16_t*)p)[idx]) << 16);
    }
    static __device__ __forceinline__ void st4(void* p, int idx, const float f[4]) {
        uint2 u;
        u.x = (uint32_t)f2bf(f[0]) | ((uint32_t)f2bf(f[1]) << 16);
        u.y = (uint32_t)f2bf(f[2]) | ((uint32_t)f2bf(f[3]) << 16);
        *(uint2*)((uint16_t*)p + idx) = u;
    }
    static __device__ __forceinline__ void st4z(void* p, int idx) {
        *(uint2*)((uint16_t*)p + idx) = make_uint2(0u, 0u);
    }
};

__device__ __forceinline__ float sigmoid_f(float x) {
    x = fminf(fmaxf(x, -30.f), 30.f);
    return 1.f / (1.f + __expf(-x));
}
__device__ __forceinline__ float tanh_f(float x) {
    x = fminf(fmaxf(x, -15.f), 15.f);
    float e = __expf(-2.f * x);
    return (1.f - e) / (1.f + e);
}

// ---------------------------------------------------------------------------
// Kernel 1: fill all_hidden_states[:, :, 256:512] with masked tree/graph
// broadcast (zeros at t >= len). 8 elements / thread. Unchanged.
// ---------------------------------------------------------------------------
template <bool F32>
__global__ __launch_bounds__(256) void latent_fill_kernel(
    const void* __restrict__ tree,
    const void* __restrict__ graph,
    const int* __restrict__ lengths,
    const void* __restrict__ Wcs_detect,
    void* __restrict__ out)
{
    __shared__ int s_is32;
    if (threadIdx.x == 0) s_is32 = detect_f32((const uint32_t*)Wcs_detect);
    __syncthreads();
    if ((s_is32 != 0) != F32) return;

    int idx = (int)(blockIdx.x * 256 + threadIdx.x);   // 0 .. B*T*32
    int c = (idx & 31) * 8;                  // 0..248 within latent cols
    int bt = idx >> 5;                       // b*T + t
    int t = bt % T_N;
    int b = bt / T_N;

    int dst = OUT_ALLH + bt * COLS + H_N + c;
    if (t < lengths[b]) {
        float v[8];
        if (c < L_N) {
            IO<F32>::ld4(tree, b * L_N + c, v);
            IO<F32>::ld4(tree, b * L_N + c + 4, v + 4);
        } else {
            IO<F32>::ld4(graph, b * L_N + (c - L_N), v);
            IO<F32>::ld4(graph, b * L_N + (c - L_N) + 4, v + 4);
        }
        IO<F32>::st4(out, dst, v);
        IO<F32>::st4(out, dst + 4, v + 4);
    } else {
        IO<F32>::st4z(out, dst);
        IO<F32>::st4z(out, dst + 4);
    }
}

// ---------------------------------------------------------------------------
// Kernel 2: k-split block-GEMM GRU, 256-thread / 256-VGPR-budget pipeline.
//   Identical structure to r8 (verified correct, 3934us) with ONE change:
//   all global indices are 32-bit. r8 pinned VGPR_Count at 256 and spilled
//   (FETCH 1.33GB scratch) because 64-bit per-load addressing cost ~60 VGPRs;
//   int indices make row offsets SGPR-uniform and share one voffset VGPR.
//   256 threads = 4 waves = 1 wave/SIMD -> 256-VGPR budget. 16-k chunks,
//   A/B double-buffered, 32 weight loads in flight per wave.
//   GEMM role: kq = tid>>7 (2 k-groups x 128 h-rows), 2 cols/thread.
//   Gate role: ro = tid>>5 (8 row-owners), 8 cols/thread.
//   hstage row-major: gate writes contiguous float4, GEMM reads same-address
//   broadcasts (conflict-free).
// ---------------------------------------------------------------------------
template <bool F32>
__global__ __launch_bounds__(256, 1) void gru_kernel(
    const void* __restrict__ x_seq,
    const void* __restrict__ hidden,
    const void* __restrict__ graph,
    const int* __restrict__ lengths,
    const void* __restrict__ Wcs, const void* __restrict__ bcs,
    const void* __restrict__ Wz,  const void* __restrict__ bz,
    const void* __restrict__ Wr,  const void* __restrict__ br,
    const void* __restrict__ Wh,  const void* __restrict__ bh,
    void* __restrict__ out)
{
    __shared__ float Pz[NKQ][RB][H_N];       // 16 KB  (aliased as cs at init)
    __shared__ float Pr[NKQ][RB][H_N];       // 16 KB
    __shared__ float hstage[RB][HSTR];       // 8.25 KB  [r][k]: h, then x
    __shared__ float gstage[RB][HSTR];       // 8.25 KB  [r][k]: r*h, then x
    __shared__ int s_is32;
    __shared__ int s_len[RB];

    if (threadIdx.x == 0) s_is32 = detect_f32((const uint32_t*)Wcs);
    __syncthreads();
    if ((s_is32 != 0) != F32) return;

    const int tid = threadIdx.x;
    const int kq  = tid >> 7;          // k-group (wave-pair uniform)
    const int c0  = (tid & 127) * 2;   // GEMM: this thread's 2 columns
    const int ro  = tid >> 5;          // gate: row owner (0..7)
    const int c0g = (tid & 31) * 8;    // gate: this thread's 8 columns
    const int kh0 = kq * KQH;          // first h-row of this k-group

    if (tid < RB) {
        int L = lengths[blockIdx.x * RB + tid];
        s_len[tid] = min(max(L, 1), T_N);
    }
    __syncthreads();

    const int b0  = blockIdx.x * RB;
    const int bo  = b0 + ro;           // owner batch row
    const int len = s_len[ro];
    int maxlen = 1;
    #pragma unroll
    for (int i = 0; i < RB; ++i) maxlen = max(maxlen, s_len[i]);

    // ---- stage [hidden, graph] into Pz alias (stride 388) ----
    {
        float* cs = &Pz[0][0][0];
        for (int i = tid; i < RB * KCS; i += 256) {
            int r = i / KCS;
            int k = i - r * KCS;
            int bb = b0 + r;
            float v = (k < H_N) ? IO<F32>::ld1(hidden, bb * H_N + k)
                                : IO<F32>::ld1(graph,  bb * L_N + (k - H_N));
            cs[r * 388 + k] = v;
        }
    }
    __syncthreads();

    // ---- h0 = relu(cs[ro] @ Wcs + bcs): gate layout, 8 cols/thread ----
    float h[8];
    {
        const float* cs = &Pz[0][0][0];
        float acc[8];
        IO<F32>::ld4(bcs, c0g, acc);
        IO<F32>::ld4(bcs, c0g + 4, acc + 4);
        for (int k = 0; k < KCS; k += 4) {
            const float4 hv = *reinterpret_cast<const float4*>(&cs[ro * 388 + k]);
            const float hvv[4] = {hv.x, hv.y, hv.z, hv.w};
            #pragma unroll
            for (int kk = 0; kk < 4; ++kk) {
                float w[8];
                IO<F32>::ld4(Wcs, (k + kk) * H_N + c0g, w);
                IO<F32>::ld4(Wcs, (k + kk) * H_N + c0g + 4, w + 4);
                #pragma unroll
                for (int j = 0; j < 8; ++j) acc[j] += hvv[kk] * w[j];
            }
        }
        #pragma unroll
        for (int j = 0; j < 8; ++j) h[j] = fmaxf(acc[j], 0.f);
    }

    // ---- biases (gate layout, loop-invariant) ----
    float bzv[8], brv[8], bhv[8];
    IO<F32>::ld4(bz, c0g, bzv); IO<F32>::ld4(bz, c0g + 4, bzv + 4);
    IO<F32>::ld4(br, c0g, brv); IO<F32>::ld4(br, c0g + 4, brv + 4);
    IO<F32>::ld4(bh, c0g, bhv); IO<F32>::ld4(bh, c0g + 4, bhv + 4);

    float smax[8];
    #pragma unroll
    for (int j = 0; j < 8; ++j) smax[j] = -1e30f;

    __syncthreads();   // all cs reads done (Pz free for partials)

    // ---- h0 -> hstage; x(0) -> hstage/gstage; prefetch x(1) ----
    *reinterpret_cast<float4*>(&hstage[ro][c0g])     = make_float4(h[0], h[1], h[2], h[3]);
    *reinterpret_cast<float4*>(&hstage[ro][c0g + 4]) = make_float4(h[4], h[5], h[6], h[7]);

    const int xr = tid / NV_N;
    const int xi = tid - xr * NV_N;
    float xv = 0.f;
    if (tid < RB * NV_N) {
        float x0 = IO<F32>::ld1(x_seq, ((b0 + xr) * T_N + 0) * NV_N + xi);
        hstage[xr][H_N + xi] = x0;
        gstage[xr][H_N + xi] = x0;
        int tn = (1 < T_N) ? 1 : 0;
        xv = IO<F32>::ld1(x_seq, ((b0 + xr) * T_N + tn) * NV_N + xi);
    }
    __syncthreads();

    float z[8];   // persists gates -> update

    // raw load buffers (bf16: 1 VGPR each)
    typename IO<F32>::Raw2 zA[CH], rA[CH], zB[CH], rB[CH], hA[CH], hB[CH];
    typename IO<F32>::Raw2 xzb[NV_N], xrb[NV_N], xhb[NV_N];

#define P1_ISSUE(CHN, RZ, RR) { \
    const int kb_ = 5 + kh0 + (CHN) * CH; \
    _Pragma("unroll") \
    for (int i_ = 0; i_ < CH; ++i_) { \
        RZ[i_] = IO<F32>::ldraw2(Wz, (kb_ + i_) * H_N + c0); \
        RR[i_] = IO<F32>::ldraw2(Wr, (kb_ + i_) * H_N + c0); \
    } \
    __builtin_amdgcn_sched_barrier(0); }

#define P1_CONSUME(CHN, RZ, RR) { \
    const int kb_ = kh0 + (CHN) * CH; \
    _Pragma("unroll") \
    for (int g_ = 0; g_ < CH / 2; ++g_) { \
        float2 hr_[RB]; \
        _Pragma("unroll") \
        for (int r_ = 0; r_ < RB; ++r_) \
            hr_[r_] = *reinterpret_cast<const float2*>(&hstage[r_][kb_ + 2 * g_]); \
        _Pragma("unroll") \
        for (int u_ = 0; u_ < 2; ++u_) { \
            float wz2_[2], wr2_[2]; \
            IO<F32>::cvt2(RZ[2 * g_ + u_], wz2_); \
            IO<F32>::cvt2(RR[2 * g_ + u_], wr2_); \
            _Pragma("unroll") \
            for (int r_ = 0; r_ < RB; ++r_) { \
                const float hv_ = u_ ? hr_[r_].y : hr_[r_].x; \
                az[r_][0] += hv_ * wz2_[0]; \
                az[r_][1] += hv_ * wz2_[1]; \
                ar[r_][0] += hv_ * wr2_[0]; \
                ar[r_][1] += hv_ * wr2_[1]; \
            } } } }

#define P2_ISSUE(CHN, RH) { \
    const int kb_ = 5 + kh0 + (CHN) * CH; \
    _Pragma("unroll") \
    for (int i_ = 0; i_ < CH; ++i_) \
        RH[i_] = IO<F32>::ldraw2(Wh, (kb_ + i_) * H_N + c0); \
    __builtin_amdgcn_sched_barrier(0); }

#define P2_CONSUME(CHN, RH) { \
    const int kb_ = kh0 + (CHN) * CH; \
    _Pragma("unroll") \
    for (int g_ = 0; g_ < CH / 2; ++g_) { \
        float2 gr_[RB]; \
        _Pragma("unroll") \
        for (int r_ = 0; r_ < RB; ++r_) \
            gr_[r_] = *reinterpret_cast<const float2*>(&gstage[r_][kb_ + 2 * g_]); \
        _Pragma("unroll") \
        for (int u_ = 0; u_ < 2; ++u_) { \
            float wh2_[2]; \
            IO<F32>::cvt2(RH[2 * g_ + u_], wh2_); \
            _Pragma("unroll") \
            for (int r_ = 0; r_ < RB; ++r_) { \
                const float gv_ = u_ ? gr_[r_].y : gr_[r_].x; \
                ag[r_][0] += gv_ * wh2_[0]; \
                ag[r_][1] += gv_ * wh2_[1]; \
            } } } }

#define PX_ISSUE() if (kq == 0) { \
    _Pragma("unroll") \
    for (int i_ = 0; i_ < NV_N; ++i_) { \
        xzb[i_] = IO<F32>::ldraw2(Wz, i_ * H_N + c0); \
        xrb[i_] = IO<F32>::ldraw2(Wr, i_ * H_N + c0); \
    } }

#define PXH_ISSUE() if (kq == 0) { \
    _Pragma("unroll") \
    for (int i_ = 0; i_ < NV_N; ++i_) \
        xhb[i_] = IO<F32>::ldraw2(Wh, i_ * H_N + c0); }

#define P1X_CONSUME() if (kq == 0) { \
    _Pragma("unroll") \
    for (int i_ = 0; i_ < NV_N; ++i_) { \
        float wz2_[2], wr2_[2]; \
        IO<F32>::cvt2(xzb[i_], wz2_); \
        IO<F32>::cvt2(xrb[i_], wr2_); \
        _Pragma("unroll") \
        for (int r_ = 0; r_ < RB; ++r_) { \
            const float xv_ = hstage[r_][H_N + i_]; \
            az[r_][0] += xv_ * wz2_[0]; \
            az[r_][1] += xv_ * wz2_[1]; \
            ar[r_][0] += xv_ * wr2_[0]; \
            ar[r_][1] += xv_ * wr2_[1]; \
        } } }

#define P2X_CONSUME() if (kq == 0) { \
    _Pragma("unroll") \
    for (int i_ = 0; i_ < NV_N; ++i_) { \
        float wh2_[2]; \
        IO<F32>::cvt2(xhb[i_], wh2_); \
        _Pragma("unroll") \
        for (int r_ = 0; r_ < RB; ++r_) { \
            const float xv_ = gstage[r_][H_N + i_]; \
            ag[r_][0] += xv_ * wh2_[0]; \
            ag[r_][1] += xv_ * wh2_[1]; \
        } } }

    // prologue: first step's pass-1 chunk 0 + x-part in flight
    PX_ISSUE();
    P1_ISSUE(0, zA, rA);

    #pragma unroll 1
    for (int t = 0; t < maxlen; ++t) {
        // ===== pass 1: partial z,r over this k-group =====
        float az[RB][2], ar[RB][2];
        #pragma unroll
        for (int r = 0; r < RB; ++r) {
            az[r][0] = 0.f; az[r][1] = 0.f;
            ar[r][0] = 0.f; ar[r][1] = 0.f;
        }
        #pragma unroll 1
        for (int ch = 0; ch < NCH; ch += 2) {
            P1_ISSUE(ch + 1, zB, rB);
            P1_CONSUME(ch, zA, rA);
            if (ch + 2 < NCH) { P1_ISSUE(ch + 2, zA, rA); }
            else              { P2_ISSUE(0, hA); PXH_ISSUE(); }
            P1_CONSUME(ch + 1, zB, rB);
        }
        P1X_CONSUME();
        #pragma unroll
        for (int r = 0; r < RB; ++r) {
            *reinterpret_cast<float2*>(&Pz[kq][r][c0]) = make_float2(az[r][0], az[r][1]);
            *reinterpret_cast<float2*>(&Pr[kq][r][c0]) = make_float2(ar[r][0], ar[r][1]);
        }
        __syncthreads();                           // B1

        // ===== gates z,r (owner: row ro, cols c0g..c0g+7) =====
        {
            float sz[8], sr[8];
            #pragma unroll
            for (int j = 0; j < 8; ++j) { sz[j] = bzv[j]; sr[j] = brv[j]; }
            #pragma unroll
            for (int q = 0; q < NKQ; ++q) {
                float4 a = *reinterpret_cast<const float4*>(&Pz[q][ro][c0g]);
                float4 b = *reinterpret_cast<const float4*>(&Pz[q][ro][c0g + 4]);
                sz[0] += a.x; sz[1] += a.y; sz[2] += a.z; sz[3] += a.w;
                sz[4] += b.x; sz[5] += b.y; sz[6] += b.z; sz[7] += b.w;
                a = *reinterpret_cast<const float4*>(&Pr[q][ro][c0g]);
                b = *reinterpret_cast<const float4*>(&Pr[q][ro][c0g + 4]);
                sr[0] += a.x; sr[1] += a.y; sr[2] += a.z; sr[3] += a.w;
                sr[4] += b.x; sr[5] += b.y; sr[6] += b.z; sr[7] += b.w;
            }
            float rh[8];
            #pragma unroll
            for (int j = 0; j < 8; ++j) {
                z[j] = sigmoid_f(sz[j]);
                rh[j] = sigmoid_f(sr[j]) * h[j];
            }
            *reinterpret_cast<float4*>(&gstage[ro][c0g])     = make_float4(rh[0], rh[1], rh[2], rh[3]);
            *reinterpret_cast<float4*>(&gstage[ro][c0g + 4]) = make_float4(rh[4], rh[5], rh[6], rh[7]);
        }
        __syncthreads();                           // B2

        // ===== pass 2: partial candidate-h =====
        float ag[RB][2];
        #pragma unroll
        for (int r = 0; r < RB; ++r) { ag[r][0] = 0.f; ag[r][1] = 0.f; }
        #pragma unroll 1
        for (int ch = 0; ch < NCH; ch += 2) {
            P2_ISSUE(ch + 1, hB);
            P2_CONSUME(ch, hA);
            if (ch + 2 < NCH) { P2_ISSUE(ch + 2, hA); }
            else              { P1_ISSUE(0, zA, rA); PX_ISSUE(); }   // next step
            P2_CONSUME(ch + 1, hB);
        }
        P2X_CONSUME();
        #pragma unroll
        for (int r = 0; r < RB; ++r)
            *reinterpret_cast<float2*>(&Pz[kq][r][c0]) = make_float2(ag[r][0], ag[r][1]);
        __syncthreads();                           // B3

        // ===== reduce + update + stores (owner) =====
        {
            float sg[8];
            #pragma unroll
            for (int j = 0; j < 8; ++j) sg[j] = bhv[j];
            #pragma unroll
            for (int q = 0; q < NKQ; ++q) {
                float4 a = *reinterpret_cast<const float4*>(&Pz[q][ro][c0g]);
                float4 b = *reinterpret_cast<const float4*>(&Pz[q][ro][c0g + 4]);
                sg[0] += a.x; sg[1] += a.y; sg[2] += a.z; sg[3] += a.w;
                sg[4] += b.x; sg[5] += b.y; sg[6] += b.z; sg[7] += b.w;
            }
            const bool active = (t < len);
            float hs[8];
            #pragma unroll
            for (int j = 0; j < 8; ++j) {
                float pre = tanh_f(sg[j]);
                float hn  = (1.f - z[j]) * h[j] + z[j] * pre;
                hn = active ? hn : h[j];
                h[j]  = hn;
                hs[j] = active ? hn : 0.f;
                smax[j] = active ? fmaxf(smax[j], hn) : smax[j];
            }
            const int ob = OUT_ALLH + (bo * T_N + t) * COLS + c0g;
            IO<F32>::st4(out, ob, hs);
            IO<F32>::st4(out, ob + 4, hs + 4);
            if (t == len - 1) {
                IO<F32>::st4(out, bo * H_N + c0g, h);
                IO<F32>::st4(out, bo * H_N + c0g + 4, h + 4);
            }
            *reinterpret_cast<float4*>(&hstage[ro][c0g])     = make_float4(h[0], h[1], h[2], h[3]);
            *reinterpret_cast<float4*>(&hstage[ro][c0g + 4]) = make_float4(h[4], h[5], h[6], h[7]);
        }
        // stage x(t+1), prefetch x(t+2)
        if (tid < RB * NV_N) {
            hstage[xr][H_N + xi] = xv;
            gstage[xr][H_N + xi] = xv;
            int tn = (t + 2 < T_N) ? (t + 2) : (T_N - 1);
            xv = IO<F32>::ld1(x_seq, ((b0 + xr) * T_N + tn) * NV_N + xi);
        }
        __syncthreads();                           // B4
    }

#undef P1_ISSUE
#undef P1_CONSUME
#undef P2_ISSUE
#undef P2_CONSUME
#undef PX_ISSUE
#undef PXH_ISSUE
#undef P1X_CONSUME
#undef P2X_CONSUME

    // zero-fill all_h h-columns for t >= maxlen (rows with len<maxlen got
    // zeros in-loop); harness poisons d_out so every element must be written
    for (int t = maxlen; t < T_N; ++t) {
        const int ob = OUT_ALLH + (bo * T_N + t) * COLS + c0g;
        IO<F32>::st4z(out, ob);
        IO<F32>::st4z(out, ob + 4);
    }
    IO<F32>::st4(out, OUT_SEG + bo * H_N + c0g, smax);
    IO<F32>::st4(out, OUT_SEG + bo * H_N + c0g + 4, smax + 4);
}

extern "C" void kernel_launch(void* const* d_in, const int* in_sizes, int n_in,
                              void* d_out, int out_size, void* d_ws, size_t ws_size,
                              hipStream_t stream) {
    const void* x_seq  = d_in[0];
    const void* hidden = d_in[1];
    const void* tree   = d_in[2];
    const void* graph  = d_in[3];
    const int*  lens   = (const int*)d_in[4];
    const void* Wcs    = d_in[5];
    const void* bcs    = d_in[6];
    const void* Wz     = d_in[7];
    const void* bz     = d_in[8];
    const void* Wr     = d_in[9];
    const void* br     = d_in[10];
    const void* Wh     = d_in[11];
    const void* bh     = d_in[12];
    void* out = d_out;

    long long work = (long long)B_N * T_N * 32;
    int fill_blocks = (int)(work / 256);   // 25600

    // Launch BOTH dtype variants; each self-selects via detect_f32 and the
    // mismatching variant exits immediately. Deterministic work per call
    // => graph-capture safe.
    hipLaunchKernelGGL((latent_fill_kernel<true>),  dim3(fill_blocks), dim3(256), 0, stream,
                       tree, graph, lens, Wcs, out);
    hipLaunchKernelGGL((latent_fill_kernel<false>), dim3(fill_blocks), dim3(256), 0, stream,
                       tree, graph, lens, Wcs, out);

    hipLaunchKernelGGL((gru_kernel<true>), dim3(B_N / RB), dim3(256), 0, stream,
                       x_seq, hidden, graph, lens,
                       Wcs, bcs, Wz, bz, Wr, br, Wh, bh, out);
    hipLaunchKernelGGL((gru_kernel<false>), dim3(B_N / RB), dim3(256), 0, stream,
                       x_seq, hidden, graph, lens,
                       Wcs, bcs, Wz, bz, Wr, br, Wh, bh, out);
}